// Round 12
// baseline (757.186 us; speedup 1.0000x reference)
//
#include <hip/hip_runtime.h>

#define B_  2
#define S_  2048
#define D_  1024
#define H_  16
#define DH_ 64

typedef _Float16 f16;
typedef f16   f16x2 __attribute__((ext_vector_type(2)));
typedef f16   f16x4 __attribute__((ext_vector_type(4)));
typedef f16   f16x8 __attribute__((ext_vector_type(8)));
typedef float f32x4 __attribute__((ext_vector_type(4)));
typedef float f32x16 __attribute__((ext_vector_type(16)));

static __device__ __forceinline__ f16x8 ldsm8(const f16* p) {
    return *reinterpret_cast<const f16x8*>(p);
}

// XOR swizzle for 128B-row LDS tiles (T2/G4).
static __device__ __forceinline__ int swz(int row, int byteInRow) {
    return row * 128 + (byteInRow ^ ((row & 7) << 4));
}

// async global->LDS DMA, 16B per lane; dest = wave-uniform base + lane*16
static __device__ __forceinline__ void gll16(const void* g, void* l) {
    __builtin_amdgcn_global_load_lds(
        (const __attribute__((address_space(1))) void*)g,
        (__attribute__((address_space(3))) void*)l, 16, 0, 0);
}

// pack two f32 -> one u32 of two f16 (RTZ), via the HW packed-convert
static __device__ __forceinline__ unsigned pk16(float a, float b) {
    return __builtin_bit_cast(unsigned, __builtin_amdgcn_cvt_pkrtz(a, b));
}

// ---------------------------------------------------------------------------
// Fused Q/K/V projection: blockIdx.z selects which of the three GEMMs.
// ---------------------------------------------------------------------------
__global__ __launch_bounds__(256)
void qkv_gemm(const float* __restrict__ Aq, const float* __restrict__ Ak,
              const float* __restrict__ Av,
              const float* __restrict__ Wq, const float* __restrict__ Wk,
              const float* __restrict__ Wv,
              const float* __restrict__ bq, const float* __restrict__ bk,
              const float* __restrict__ bv,
              f16* __restrict__ qo, f16* __restrict__ ko, f16* __restrict__ vo,
              float qscale)
{
    constexpr int K = 1024, N = 1024;
    __shared__ __align__(16) f16 As[128][40];
    __shared__ __align__(16) f16 Bs[128][40];
    const int z = blockIdx.z;
    const float* A    = z == 0 ? Aq : z == 1 ? Ak : Av;
    const float* W    = z == 0 ? Wq : z == 1 ? Wk : Wv;
    const float* bias = z == 0 ? bq : z == 1 ? bk : bv;
    const float scale = z == 0 ? qscale : 1.0f;

    const int t  = threadIdx.x;
    const int bm = blockIdx.y * 128;
    const int bn = blockIdx.x * 128;
    const int w  = t >> 6, l = t & 63;
    const int wr = w >> 1, wc = w & 1;
    const int lr = l & 15, lg = l >> 4;

    f32x4 acc[4][4];
    #pragma unroll
    for (int m = 0; m < 4; ++m)
        #pragma unroll
        for (int n = 0; n < 4; ++n)
            acc[m][n] = (f32x4){0.f, 0.f, 0.f, 0.f};

    for (int kt = 0; kt < K / 32; ++kt) {
        #pragma unroll
        for (int i = 0; i < 4; ++i) {
            int idx = t + i * 256;
            int row = idx >> 3, g = idx & 7;
            float4 v = *reinterpret_cast<const float4*>(A + (size_t)(bm + row) * K + kt * 32 + g * 4);
            alignas(8) f16 hh[4] = {(f16)v.x, (f16)v.y, (f16)v.z, (f16)v.w};
            *reinterpret_cast<uint2*>(&As[row][g * 4]) = *reinterpret_cast<uint2*>(hh);
        }
        #pragma unroll
        for (int i = 0; i < 4; ++i) {
            int idx = t + i * 256;
            int row = idx >> 3, g = idx & 7;
            float4 v = *reinterpret_cast<const float4*>(W + (size_t)(bn + row) * K + kt * 32 + g * 4);
            alignas(8) f16 hh[4] = {(f16)v.x, (f16)v.y, (f16)v.z, (f16)v.w};
            *reinterpret_cast<uint2*>(&Bs[row][g * 4]) = *reinterpret_cast<uint2*>(hh);
        }
        __syncthreads();

        f16x8 af[4], bfv[4];
        #pragma unroll
        for (int m = 0; m < 4; ++m) af[m]  = ldsm8(&As[wr * 64 + m * 16 + lr][lg * 8]);
        #pragma unroll
        for (int n = 0; n < 4; ++n) bfv[n] = ldsm8(&Bs[wc * 64 + n * 16 + lr][lg * 8]);
        #pragma unroll
        for (int m = 0; m < 4; ++m)
            #pragma unroll
            for (int n = 0; n < 4; ++n)
                acc[m][n] = __builtin_amdgcn_mfma_f32_16x16x32_f16(af[m], bfv[n], acc[m][n], 0, 0, 0);
        __syncthreads();
    }

    #pragma unroll
    for (int m = 0; m < 4; ++m) {
        #pragma unroll
        for (int n = 0; n < 4; ++n) {
            int col = bn + wc * 64 + n * 16 + lr;
            float bb = bias[col];
            if (z == 2) {
                int row0 = bm + wr * 64 + m * 16 + lg * 4;
                int b = row0 >> 11, s = row0 & 2047;
                int hh_ = col >> 6, d = col & 63;
                alignas(8) f16 hv[4];
                #pragma unroll
                for (int j = 0; j < 4; ++j)
                    hv[j] = (f16)(acc[m][n][j] + bb);
                *reinterpret_cast<uint2*>(vo +
                    (((size_t)(b * 16 + hh_) * 64 + d) * 2048 + s)) =
                    *reinterpret_cast<uint2*>(hv);
            } else {
                f16* Cp = z == 0 ? qo : ko;
                #pragma unroll
                for (int j = 0; j < 4; ++j) {
                    int row = bm + wr * 64 + m * 16 + lg * 4 + j;
                    Cp[(size_t)row * N + col] = (f16)((acc[m][n][j] + bb) * scale);
                }
            }
        }
    }
}

// C[M,N] = A[M,K] @ W[N,K]^T (+bias).  A f16, out f32 (out-projection).
__global__ __launch_bounds__(256)
void gemm_out(const f16* __restrict__ A, const float* __restrict__ W,
              const float* __restrict__ bias, float* __restrict__ Cp)
{
    constexpr int K = 1024, N = 1024;
    __shared__ __align__(16) f16 As[128][40];
    __shared__ __align__(16) f16 Bs[128][40];
    const int t  = threadIdx.x;
    const int bm = blockIdx.y * 128;
    const int bn = blockIdx.x * 128;
    const int w  = t >> 6, l = t & 63;
    const int wr = w >> 1, wc = w & 1;
    const int lr = l & 15, lg = l >> 4;

    f32x4 acc[4][4];
    #pragma unroll
    for (int m = 0; m < 4; ++m)
        #pragma unroll
        for (int n = 0; n < 4; ++n)
            acc[m][n] = (f32x4){0.f, 0.f, 0.f, 0.f};

    for (int kt = 0; kt < K / 32; ++kt) {
        #pragma unroll
        for (int i = 0; i < 2; ++i) {
            int idx = t + i * 256;
            int row = idx >> 2, g = idx & 3;
            *reinterpret_cast<uint4*>(&As[row][g * 8]) =
                *reinterpret_cast<const uint4*>(A + (size_t)(bm + row) * K + kt * 32 + g * 8);
        }
        #pragma unroll
        for (int i = 0; i < 4; ++i) {
            int idx = t + i * 256;
            int row = idx >> 3, g = idx & 7;
            float4 v = *reinterpret_cast<const float4*>(W + (size_t)(bn + row) * K + kt * 32 + g * 4);
            alignas(8) f16 hh[4] = {(f16)v.x, (f16)v.y, (f16)v.z, (f16)v.w};
            *reinterpret_cast<uint2*>(&Bs[row][g * 4]) = *reinterpret_cast<uint2*>(hh);
        }
        __syncthreads();

        f16x8 af[4], bfv[4];
        #pragma unroll
        for (int m = 0; m < 4; ++m) af[m]  = ldsm8(&As[wr * 64 + m * 16 + lr][lg * 8]);
        #pragma unroll
        for (int n = 0; n < 4; ++n) bfv[n] = ldsm8(&Bs[wc * 64 + n * 16 + lr][lg * 8]);
        #pragma unroll
        for (int m = 0; m < 4; ++m)
            #pragma unroll
            for (int n = 0; n < 4; ++n)
                acc[m][n] = __builtin_amdgcn_mfma_f32_16x16x32_f16(af[m], bfv[n], acc[m][n], 0, 0, 0);
        __syncthreads();
    }

    #pragma unroll
    for (int m = 0; m < 4; ++m) {
        #pragma unroll
        for (int n = 0; n < 4; ++n) {
            int col = bn + wc * 64 + n * 16 + lr;
            float bb = bias[col];
            #pragma unroll
            for (int j = 0; j < 4; ++j) {
                int row = bm + wr * 64 + m * 16 + lg * 4 + j;
                Cp[(size_t)row * N + col] = acc[m][n][j] + bb;
            }
        }
    }
}

// Lean denominator kernel: one block per (b, h, 128-row q-tile), 512 threads.
__global__ __launch_bounds__(512, 4)
void k_sums(const f16* __restrict__ qh, const f16* __restrict__ khp,
            const int* __restrict__ kmask, float* __restrict__ linv_g)
{
    __shared__ __align__(16) f16 ksd[2][64 * 64];
    __shared__ float red[4][32];
    __shared__ unsigned mbits[64];

    const int t  = threadIdx.x;
    const int w  = t >> 6, l = t & 63, lo = l & 31, hi = l >> 5;
    const int wq = w >> 1, wk = w & 1;

    const int bid  = blockIdx.x;
    const int xcd  = bid & 7;
    const int slot = bid >> 3;
    const int bh   = (xcd << 2) | (slot >> 4);
    const int qt   = slot & 15;
    const int b    = bh >> 4;
    const int h    = bh & 15;
    const int q0   = qt * 128;

    f16x8 qf[4];
    {
        const f16* qb = qh + (size_t)(b * S_ + q0 + wq * 32 + lo) * D_ + h * DH_ + hi * 8;
        #pragma unroll
        for (int c = 0; c < 4; ++c) qf[c] = *reinterpret_cast<const f16x8*>(qb + c * 16);
    }

    #pragma unroll
    for (int r = 0; r < 4; ++r) {
        int ktm = w * 4 + r;
        int mkv = kmask[b * S_ + ktm * 64 + l];
        unsigned long long bl = __ballot(mkv != 0);
        if (l == 0) {
            mbits[ktm * 2]     = (unsigned)bl;
            mbits[ktm * 2 + 1] = (unsigned)(bl >> 32);
        }
    }

    const int r8 = l >> 3, l8 = l & 7;
    const int xorc8 = (l8 ^ r8) * 8;
    const f16* kgb = khp + (size_t)b * S_ * D_ + h * DH_;
    const int krow = wk * 32 + lo;

    auto stageK = [&](int buf, int kt) {
        int row = w * 8 + r8;
        gll16(kgb + (size_t)(kt * 64 + row) * D_ + xorc8,
              (char*)ksd[buf] + w * 1024);
    };

    stageK(0, 0);
    __syncthreads();

    float ls = 0.f;
    int cur = 0;
    for (int kt = 0; kt < 32; ++kt) {
        if (kt + 1 < 32) stageK(cur ^ 1, kt + 1);

        const unsigned mshift = mbits[kt * 2 + wk] >> (hi * 4);

        f32x16 s;
        #pragma unroll
        for (int i = 0; i < 16; ++i) s[i] = 0.f;
        #pragma unroll
        for (int c = 0; c < 4; ++c) {
            f16x8 kf = *reinterpret_cast<const f16x8*>(
                (const char*)ksd[cur] + swz(krow, c * 32 + hi * 16));
            s = __builtin_amdgcn_mfma_f32_32x32x16_f16(kf, qf[c], s, 0, 0, 0);
        }
        #pragma unroll
        for (int q4 = 0; q4 < 4; ++q4)
            #pragma unroll
            for (int j = 0; j < 4; ++j) {
                float e = __builtin_amdgcn_exp2f(s[q4 * 4 + j]);
                ls += ((mshift >> (q4 * 8 + j)) & 1) ? e : 0.0f;
            }
        __syncthreads();
        cur ^= 1;
    }

    ls += __shfl_xor(ls, 32, 64);
    if (wk == 1 && hi == 0) red[wq][lo] = ls;
    __syncthreads();
    if (wk == 0 && hi == 0)
        linv_g[(size_t)bh * S_ + q0 + wq * 32 + lo] = 1.0f / (ls + red[wq][lo]);
}

// Pass-2 fused kernel (identical to R11).
__global__ __launch_bounds__(256, 3)
void attn_fused(const f16* __restrict__ qh, const f16* __restrict__ khp,
                const f16* __restrict__ vtg, const int* __restrict__ kmask,
                const float* __restrict__ linv_g,
                float* __restrict__ attn_out, f16* __restrict__ ch)
{
    __shared__ __align__(16) f16 ksd[3][64 * 64];   // K 3-buf (swizzled content)
    __shared__ __align__(16) f16 vsd[3][64 * 64];   // V^T 3-buf
    __shared__ unsigned mbits[64];

    const int t   = threadIdx.x;
    const int w   = t >> 6, l = t & 63, lo = l & 31, hi = l >> 5;
    const int qh_ = w & 1, kh_ = w >> 1;

    const int bid  = blockIdx.x;
    const int xcd  = bid & 7;
    const int slot = bid >> 3;
    const int bh   = (xcd << 2) | (slot >> 5);
    const int qt   = slot & 31;
    const int b    = bh >> 4;
    const int h    = bh & 15;
    const int q0   = qt * 64;

    const float invl = linv_g[(size_t)bh * S_ + q0 + qh_ * 32 + lo];

    f16x8 qf[4];
    {
        const f16* qb = qh + (size_t)(b * S_ + q0 + qh_ * 32 + lo) * D_ + h * DH_ + hi * 8;
        #pragma unroll
        for (int c = 0; c < 4; ++c) qf[c] = *reinterpret_cast<const f16x8*>(qb + c * 16);
    }

    // mask bits: 4 waves x 8 rounds
    #pragma unroll
    for (int r = 0; r < 8; ++r) {
        int ktm = w * 8 + r;
        int mkv = kmask[b * S_ + ktm * 64 + l];
        unsigned long long bl = __ballot(mkv != 0);
        if (l == 0) {
            mbits[ktm * 2]     = (unsigned)bl;
            mbits[ktm * 2 + 1] = (unsigned)(bl >> 32);
        }
    }

    const int r8 = l >> 3, l8 = l & 7;
    const int xorc8 = (l8 ^ r8) * 8;
    const f16* kgb = khp + (size_t)b * S_ * D_ + h * DH_;
    const f16* vgb = vtg + (size_t)(bh * 64) * S_;
    const int krow = kh_ * 32 + lo;

    auto stageKV = [&](int buf, int kt) {
        #pragma unroll
        for (int i = 0; i < 2; ++i) {
            int row = i * 32 + w * 8 + r8;
            gll16(kgb + (size_t)(kt * 64 + row) * D_ + xorc8,
                  (char*)ksd + buf * 8192 + i * 4096 + w * 1024);
            gll16(vgb + (size_t)row * S_ + kt * 64 + xorc8,
                  (char*)vsd + buf * 8192 + i * 4096 + w * 1024);
        }
    };

    stageKV(0, 0);                    // 4 vmem ops
    stageKV(1, 1);                    // 4 vmem ops
    asm volatile("s_waitcnt vmcnt(4) lgkmcnt(0)" ::: "memory");
    __builtin_amdgcn_s_barrier();

    f32x16 oc0, oc1;
    #pragma unroll
    for (int i = 0; i < 16; ++i) { oc0[i] = 0.f; oc1[i] = 0.f; }
    int cur = 0;

    float* ab = attn_out + ((size_t)((b * H_ + h) * S_ + q0 + qh_ * 32 + lo)) * S_
                + kh_ * 32 + hi * 4;

    for (int kt = 0; kt < 32; ++kt) {
        if (kt + 2 < 32) {
            int stg = cur + 2; if (stg >= 3) stg -= 3;
            stageKV(stg, kt + 2);     // 4 vmem ops, 2 iterations ahead
        }

        const unsigned mshift = mbits[kt * 2 + kh_] >> (hi * 4);

        f32x16 s;
        #pragma unroll
        for (int i = 0; i < 16; ++i) s[i] = 0.f;
        #pragma unroll
        for (int c = 0; c < 4; ++c) {
            f16x8 kf = *reinterpret_cast<const f16x8*>(
                (const char*)ksd + cur * 8192 + swz(krow, c * 32 + hi * 16));
            s = __builtin_amdgcn_mfma_f32_32x32x16_f16(kf, qf[c], s, 0, 0, 0);
        }

        float p[16];
        #pragma unroll
        for (int q4 = 0; q4 < 4; ++q4)
            #pragma unroll
            for (int j = 0; j < 4; ++j) {
                float e = __builtin_amdgcn_exp2f(s[q4 * 4 + j]);
                p[q4 * 4 + j] = ((mshift >> (q4 * 8 + j)) & 1) ? e : 0.0f;
            }

        // normalized attn store, plain (L2 write-back combines lines)
        #pragma unroll
        for (int q4 = 0; q4 < 4; ++q4) {
            f32x4 o = {p[q4 * 4 + 0] * invl, p[q4 * 4 + 1] * invl,
                       p[q4 * 4 + 2] * invl, p[q4 * 4 + 3] * invl};
            *reinterpret_cast<f32x4*>(ab + (size_t)kt * 64 + q4 * 8) = o;
        }

        // PV: B-frag from in-register P via cvt_pkrtz + half-wave exchange
        #pragma unroll
        for (int j2 = 0; j2 < 2; ++j2) {
            unsigned wds[4], ods[4];
            #pragma unroll
            for (int i = 0; i < 4; ++i)
                wds[i] = pk16(p[8 * j2 + 2 * i], p[8 * j2 + 2 * i + 1]);
            #pragma unroll
            for (int i = 0; i < 4; ++i)
                ods[i] = (unsigned)__shfl_xor((int)wds[i], 32, 64);
            uint4 bw = (hi == 0) ? (uint4){wds[0], wds[1], ods[0], ods[1]}
                                 : (uint4){ods[2], ods[3], wds[2], wds[3]};
            f16x8 bf = __builtin_bit_cast(f16x8, bw);

            int bir = kh_ * 64 + j2 * 32 + hi * 16;
            f16x8 va0 = *reinterpret_cast<const f16x8*>(
                (const char*)vsd + cur * 8192 + swz(lo, bir));
            f16x8 va1 = *reinterpret_cast<const f16x8*>(
                (const char*)vsd + cur * 8192 + swz(lo + 32, bir));
            oc0 = __builtin_amdgcn_mfma_f32_32x32x16_f16(va0, bf, oc0, 0, 0, 0);
            oc1 = __builtin_amdgcn_mfma_f32_32x32x16_f16(va1, bf, oc1, 0, 0, 0);
        }

        asm volatile("s_waitcnt vmcnt(8)" ::: "memory");
        __builtin_amdgcn_s_barrier();
        ++cur; if (cur >= 3) cur -= 3;
    }

    // ---- cross-wave (kh) ctx reduction, 2 rounds through ksd scratch ----
    float* psf = reinterpret_cast<float*>(&ksd[0][0]);
    __syncthreads();
    #pragma unroll
    for (int g = 0; g < 2; ++g) {
        if (kh_ == 1 && qh_ == g) {
            #pragma unroll
            for (int r = 0; r < 16; ++r) {
                int d0 = (r & 3) + 8 * (r >> 2) + 4 * hi;
                psf[d0 * 32 + lo]        = oc0[r];
                psf[(32 + d0) * 32 + lo] = oc1[r];
            }
        }
        __syncthreads();
        if (kh_ == 0 && qh_ == g) {
            f16* cb = ch + (size_t)(b * S_ + q0 + g * 32 + lo) * D_ + h * DH_;
            #pragma unroll
            for (int q4 = 0; q4 < 4; ++q4) {
                int d0 = 8 * q4 + 4 * hi;
                f16x4 v0, v1;
                #pragma unroll
                for (int j = 0; j < 4; ++j) {
                    int r = 4 * q4 + j;
                    int dd = (r & 3) + 8 * (r >> 2) + 4 * hi;
                    v0[j] = (f16)((oc0[r] + psf[dd * 32 + lo]) * invl);
                    v1[j] = (f16)((oc1[r] + psf[(32 + dd) * 32 + lo]) * invl);
                }
                *reinterpret_cast<f16x4*>(cb + d0) = v0;
                *reinterpret_cast<f16x4*>(cb + 32 + d0) = v1;
            }
        }
        __syncthreads();
    }
}

extern "C" void kernel_launch(void* const* d_in, const int* in_sizes, int n_in,
                              void* d_out, int out_size, void* d_ws, size_t ws_size,
                              hipStream_t stream) {
    const float* query = (const float*)d_in[0];
    const float* key   = (const float*)d_in[1];
    const float* value = (const float*)d_in[2];
    const int*   kmask = (const int*)d_in[3];
    const float* Wq = (const float*)d_in[4];
    const float* bq = (const float*)d_in[5];
    const float* Wk = (const float*)d_in[6];
    const float* bk = (const float*)d_in[7];
    const float* Wv = (const float*)d_in[8];
    const float* bv = (const float*)d_in[9];
    const float* Wo = (const float*)d_in[10];
    const float* bo = (const float*)d_in[11];

    float* out  = (float*)d_out;
    float* attn = out + (size_t)B_ * S_ * D_;

    const size_t NE = (size_t)B_ * S_ * D_;
    f16* qhp = (f16*)d_ws;
    f16* khp = qhp + NE;
    f16* vtg = khp + NE;             // per-head transposed V: [(b*16+h)*64+d][s]
    f16* chx = vtg + NE;
    float* linv_g = (float*)(chx + NE);   // B*H*S floats (256KB); ws total 32.25MB

    const float qscale = 0.125f * 1.44269504088896340736f;   // (1/sqrt(DH)) * log2(e)

    qkv_gemm<<<dim3(8, 32, 3), 256, 0, stream>>>(query, key, value, Wq, Wk, Wv,
                                                 bq, bk, bv, qhp, khp, vtg, qscale);

    k_sums<<<dim3(B_ * H_ * (S_ / 128)), dim3(512), 0, stream>>>(qhp, khp, kmask, linv_g);

    // MEASUREMENT ROUND: attn_fused launched 3x (idempotent — reads only ws
    // buffers, rewrites identical outputs).  dur_us - baseline(335) = 2*t_attn.
    attn_fused<<<dim3(B_ * H_ * (S_ / 64)), 256, 0, stream>>>(qhp, khp, vtg, kmask,
                                                              linv_g, attn, chx);
    attn_fused<<<dim3(B_ * H_ * (S_ / 64)), 256, 0, stream>>>(qhp, khp, vtg, kmask,
                                                              linv_g, attn, chx);
    attn_fused<<<dim3(B_ * H_ * (S_ / 64)), 256, 0, stream>>>(qhp, khp, vtg, kmask,
                                                              linv_g, attn, chx);

    gemm_out<<<dim3(8, 32), 256, 0, stream>>>(chx, Wo, bo, out);
}

// Round 13
// 334.835 us; speedup vs baseline: 2.2614x; 2.2614x over previous
//
#include <hip/hip_runtime.h>

#define B_  2
#define S_  2048
#define D_  1024
#define H_  16
#define DH_ 64

typedef _Float16 f16;
typedef f16   f16x2 __attribute__((ext_vector_type(2)));
typedef f16   f16x4 __attribute__((ext_vector_type(4)));
typedef f16   f16x8 __attribute__((ext_vector_type(8)));
typedef float f32x4 __attribute__((ext_vector_type(4)));
typedef float f32x16 __attribute__((ext_vector_type(16)));

static __device__ __forceinline__ f16x8 ldsm8(const f16* p) {
    return *reinterpret_cast<const f16x8*>(p);
}

// XOR swizzle for 128B-row LDS tiles (T2/G4).
static __device__ __forceinline__ int swz(int row, int byteInRow) {
    return row * 128 + (byteInRow ^ ((row & 7) << 4));
}

// async global->LDS DMA, 16B per lane; dest = wave-uniform base + lane*16
static __device__ __forceinline__ void gll16(const void* g, void* l) {
    __builtin_amdgcn_global_load_lds(
        (const __attribute__((address_space(1))) void*)g,
        (__attribute__((address_space(3))) void*)l, 16, 0, 0);
}

// pack two f32 -> one u32 of two f16 (RTZ), via the HW packed-convert
static __device__ __forceinline__ unsigned pk16(float a, float b) {
    return __builtin_bit_cast(unsigned, __builtin_amdgcn_cvt_pkrtz(a, b));
}

// ---------------------------------------------------------------------------
// Fused Q/K/V projection: blockIdx.z selects which of the three GEMMs.
// ---------------------------------------------------------------------------
__global__ __launch_bounds__(256)
void qkv_gemm(const float* __restrict__ Aq, const float* __restrict__ Ak,
              const float* __restrict__ Av,
              const float* __restrict__ Wq, const float* __restrict__ Wk,
              const float* __restrict__ Wv,
              const float* __restrict__ bq, const float* __restrict__ bk,
              const float* __restrict__ bv,
              f16* __restrict__ qo, f16* __restrict__ ko, f16* __restrict__ vo,
              float qscale)
{
    constexpr int K = 1024, N = 1024;
    __shared__ __align__(16) f16 As[128][40];
    __shared__ __align__(16) f16 Bs[128][40];
    const int z = blockIdx.z;
    const float* A    = z == 0 ? Aq : z == 1 ? Ak : Av;
    const float* W    = z == 0 ? Wq : z == 1 ? Wk : Wv;
    const float* bias = z == 0 ? bq : z == 1 ? bk : bv;
    const float scale = z == 0 ? qscale : 1.0f;

    const int t  = threadIdx.x;
    const int bm = blockIdx.y * 128;
    const int bn = blockIdx.x * 128;
    const int w  = t >> 6, l = t & 63;
    const int wr = w >> 1, wc = w & 1;
    const int lr = l & 15, lg = l >> 4;

    f32x4 acc[4][4];
    #pragma unroll
    for (int m = 0; m < 4; ++m)
        #pragma unroll
        for (int n = 0; n < 4; ++n)
            acc[m][n] = (f32x4){0.f, 0.f, 0.f, 0.f};

    for (int kt = 0; kt < K / 32; ++kt) {
        #pragma unroll
        for (int i = 0; i < 4; ++i) {
            int idx = t + i * 256;
            int row = idx >> 3, g = idx & 7;
            float4 v = *reinterpret_cast<const float4*>(A + (size_t)(bm + row) * K + kt * 32 + g * 4);
            alignas(8) f16 hh[4] = {(f16)v.x, (f16)v.y, (f16)v.z, (f16)v.w};
            *reinterpret_cast<uint2*>(&As[row][g * 4]) = *reinterpret_cast<uint2*>(hh);
        }
        #pragma unroll
        for (int i = 0; i < 4; ++i) {
            int idx = t + i * 256;
            int row = idx >> 3, g = idx & 7;
            float4 v = *reinterpret_cast<const float4*>(W + (size_t)(bn + row) * K + kt * 32 + g * 4);
            alignas(8) f16 hh[4] = {(f16)v.x, (f16)v.y, (f16)v.z, (f16)v.w};
            *reinterpret_cast<uint2*>(&Bs[row][g * 4]) = *reinterpret_cast<uint2*>(hh);
        }
        __syncthreads();

        f16x8 af[4], bfv[4];
        #pragma unroll
        for (int m = 0; m < 4; ++m) af[m]  = ldsm8(&As[wr * 64 + m * 16 + lr][lg * 8]);
        #pragma unroll
        for (int n = 0; n < 4; ++n) bfv[n] = ldsm8(&Bs[wc * 64 + n * 16 + lr][lg * 8]);
        #pragma unroll
        for (int m = 0; m < 4; ++m)
            #pragma unroll
            for (int n = 0; n < 4; ++n)
                acc[m][n] = __builtin_amdgcn_mfma_f32_16x16x32_f16(af[m], bfv[n], acc[m][n], 0, 0, 0);
        __syncthreads();
    }

    #pragma unroll
    for (int m = 0; m < 4; ++m) {
        #pragma unroll
        for (int n = 0; n < 4; ++n) {
            int col = bn + wc * 64 + n * 16 + lr;
            float bb = bias[col];
            if (z == 2) {
                int row0 = bm + wr * 64 + m * 16 + lg * 4;
                int b = row0 >> 11, s = row0 & 2047;
                int hh_ = col >> 6, d = col & 63;
                alignas(8) f16 hv[4];
                #pragma unroll
                for (int j = 0; j < 4; ++j)
                    hv[j] = (f16)(acc[m][n][j] + bb);
                *reinterpret_cast<uint2*>(vo +
                    (((size_t)(b * 16 + hh_) * 64 + d) * 2048 + s)) =
                    *reinterpret_cast<uint2*>(hv);
            } else {
                f16* Cp = z == 0 ? qo : ko;
                #pragma unroll
                for (int j = 0; j < 4; ++j) {
                    int row = bm + wr * 64 + m * 16 + lg * 4 + j;
                    Cp[(size_t)row * N + col] = (f16)((acc[m][n][j] + bb) * scale);
                }
            }
        }
    }
}

// C[M,N] = A[M,K] @ W[N,K]^T (+bias).  A f16, out f32 (out-projection).
__global__ __launch_bounds__(256)
void gemm_out(const f16* __restrict__ A, const float* __restrict__ W,
              const float* __restrict__ bias, float* __restrict__ Cp)
{
    constexpr int K = 1024, N = 1024;
    __shared__ __align__(16) f16 As[128][40];
    __shared__ __align__(16) f16 Bs[128][40];
    const int t  = threadIdx.x;
    const int bm = blockIdx.y * 128;
    const int bn = blockIdx.x * 128;
    const int w  = t >> 6, l = t & 63;
    const int wr = w >> 1, wc = w & 1;
    const int lr = l & 15, lg = l >> 4;

    f32x4 acc[4][4];
    #pragma unroll
    for (int m = 0; m < 4; ++m)
        #pragma unroll
        for (int n = 0; n < 4; ++n)
            acc[m][n] = (f32x4){0.f, 0.f, 0.f, 0.f};

    for (int kt = 0; kt < K / 32; ++kt) {
        #pragma unroll
        for (int i = 0; i < 2; ++i) {
            int idx = t + i * 256;
            int row = idx >> 2, g = idx & 3;
            *reinterpret_cast<uint4*>(&As[row][g * 8]) =
                *reinterpret_cast<const uint4*>(A + (size_t)(bm + row) * K + kt * 32 + g * 8);
        }
        #pragma unroll
        for (int i = 0; i < 4; ++i) {
            int idx = t + i * 256;
            int row = idx >> 3, g = idx & 7;
            float4 v = *reinterpret_cast<const float4*>(W + (size_t)(bn + row) * K + kt * 32 + g * 4);
            alignas(8) f16 hh[4] = {(f16)v.x, (f16)v.y, (f16)v.z, (f16)v.w};
            *reinterpret_cast<uint2*>(&Bs[row][g * 4]) = *reinterpret_cast<uint2*>(hh);
        }
        __syncthreads();

        f16x8 af[4], bfv[4];
        #pragma unroll
        for (int m = 0; m < 4; ++m) af[m]  = ldsm8(&As[wr * 64 + m * 16 + lr][lg * 8]);
        #pragma unroll
        for (int n = 0; n < 4; ++n) bfv[n] = ldsm8(&Bs[wc * 64 + n * 16 + lr][lg * 8]);
        #pragma unroll
        for (int m = 0; m < 4; ++m)
            #pragma unroll
            for (int n = 0; n < 4; ++n)
                acc[m][n] = __builtin_amdgcn_mfma_f32_16x16x32_f16(af[m], bfv[n], acc[m][n], 0, 0, 0);
        __syncthreads();
    }

    #pragma unroll
    for (int m = 0; m < 4; ++m) {
        #pragma unroll
        for (int n = 0; n < 4; ++n) {
            int col = bn + wc * 64 + n * 16 + lr;
            float bb = bias[col];
            #pragma unroll
            for (int j = 0; j < 4; ++j) {
                int row = bm + wr * 64 + m * 16 + lg * 4 + j;
                Cp[(size_t)row * N + col] = acc[m][n][j] + bb;
            }
        }
    }
}

// ---------------------------------------------------------------------------
// Fused two-pass attention.  Block = 4 waves x 32 q-rows (QBLK=128); each
// wave processes the FULL 64-wide KV tile for its own rows (no k-split, no
// cross-wave reduction).  Pass 1: QK^T + exp-sum -> per-lane denominators
// (Q stays in registers).  Pass 2: recompute, write normalized fp32 attn
// (256B contiguous per row per tile), PV via in-register P-frag packing.
// K/V DMA-staged (pre-swizzled source), dbuf, ONE barrier per tile.
// ---------------------------------------------------------------------------
__global__ __launch_bounds__(256, 3)
void attn_fused(const f16* __restrict__ qh, const f16* __restrict__ khp,
                const f16* __restrict__ vtg, const int* __restrict__ kmask,
                float* __restrict__ attn_out, f16* __restrict__ ch)
{
    __shared__ __align__(16) f16 ksd[2][64 * 64];   // K dbuf (swizzled content)
    __shared__ __align__(16) f16 vsd[2][64 * 64];   // V^T dbuf
    __shared__ unsigned mbits[64];

    const int t  = threadIdx.x;
    const int w  = t >> 6, l = t & 63, lo = l & 31, hi = l >> 5;
    const bool H1 = (hi == 1);

    // 512 blocks = 8 xcd * 4 bh * 16 qt (all q-tiles of a (b,h) on one XCD)
    const int bid  = blockIdx.x;
    const int xcd  = bid & 7;
    const int slot = bid >> 3;
    const int bh   = (xcd << 2) | (slot >> 4);
    const int qt   = slot & 15;
    const int b    = bh >> 4;
    const int h    = bh & 15;
    const int q0   = qt * 128;
    const int row  = q0 + w * 32 + lo;       // this lane's q-row

    // Q fragments: lane holds its row's full D=64 (frag c: d = c*16 + hi*8..+8)
    f16x8 qf[4];
    {
        const f16* qb = qh + (size_t)(b * S_ + row) * D_ + h * DH_ + hi * 8;
        #pragma unroll
        for (int c = 0; c < 4; ++c) qf[c] = *reinterpret_cast<const f16x8*>(qb + c * 16);
    }

    // mask bits: 4 waves x 8 rounds
    #pragma unroll
    for (int r = 0; r < 8; ++r) {
        int ktm = w * 8 + r;
        int mkv = kmask[b * S_ + ktm * 64 + l];
        unsigned long long bl = __ballot(mkv != 0);
        if (l == 0) {
            mbits[ktm * 2]     = (unsigned)bl;
            mbits[ktm * 2 + 1] = (unsigned)(bl >> 32);
        }
    }

    const int r8 = l >> 3, l8 = l & 7;
    const int xorc8 = (l8 ^ r8) * 8;          // pre-XORed source chunk
    const f16* kgb = khp + (size_t)b * S_ * D_ + h * DH_;
    const f16* vgb = vtg + (size_t)(bh * 64) * S_;

    auto stageK = [&](int buf, int kt) {
        #pragma unroll
        for (int i = 0; i < 2; ++i) {
            int rr = i * 32 + w * 8 + r8;
            gll16(kgb + (size_t)(kt * 64 + rr) * D_ + xorc8,
                  (char*)ksd + buf * 8192 + i * 4096 + w * 1024);
        }
    };
    auto stageV = [&](int buf, int kt) {
        #pragma unroll
        for (int i = 0; i < 2; ++i) {
            int rr = i * 32 + w * 8 + r8;
            gll16(vgb + (size_t)rr * S_ + kt * 64 + xorc8,
                  (char*)vsd + buf * 8192 + i * 4096 + w * 1024);
        }
    };

    // ================= pass 1: row denominators =================
    stageK(0, 0);
    __syncthreads();

    float ls = 0.f;
    int cur = 0;
    for (int kt = 0; kt < 32; ++kt) {
        if (kt + 1 < 32) stageK(cur ^ 1, kt + 1);

        f32x16 s0, s1;
        #pragma unroll
        for (int i = 0; i < 16; ++i) { s0[i] = 0.f; s1[i] = 0.f; }
        #pragma unroll
        for (int c = 0; c < 4; ++c) {
            f16x8 kf = *reinterpret_cast<const f16x8*>(
                (const char*)ksd + cur * 8192 + swz(lo, c * 32 + hi * 16));
            s0 = __builtin_amdgcn_mfma_f32_32x32x16_f16(kf, qf[c], s0, 0, 0, 0);
        }
        #pragma unroll
        for (int c = 0; c < 4; ++c) {
            f16x8 kf = *reinterpret_cast<const f16x8*>(
                (const char*)ksd + cur * 8192 + swz(lo + 32, c * 32 + hi * 16));
            s1 = __builtin_amdgcn_mfma_f32_32x32x16_f16(kf, qf[c], s1, 0, 0, 0);
        }

        const unsigned m0 = mbits[kt * 2]     >> (hi * 4);
        const unsigned m1 = mbits[kt * 2 + 1] >> (hi * 4);
        #pragma unroll
        for (int q4 = 0; q4 < 4; ++q4)
            #pragma unroll
            for (int j = 0; j < 4; ++j) {
                float e0 = __builtin_amdgcn_exp2f(s0[q4 * 4 + j]);
                float e1 = __builtin_amdgcn_exp2f(s1[q4 * 4 + j]);
                ls += ((m0 >> (q4 * 8 + j)) & 1) ? e0 : 0.0f;
                ls += ((m1 >> (q4 * 8 + j)) & 1) ? e1 : 0.0f;
            }
        __syncthreads();
        cur ^= 1;
    }

    ls += __shfl_xor(ls, 32, 64);     // combine the two hi-halves of each row
    const float invl = 1.0f / ls;

    // ================= pass 2: write attn + PV =================
    stageK(0, 0);
    stageV(0, 0);
    __syncthreads();

    f32x16 oc0, oc1;
    #pragma unroll
    for (int i = 0; i < 16; ++i) { oc0[i] = 0.f; oc1[i] = 0.f; }
    cur = 0;

    float* ab = attn_out + ((size_t)bh * S_ + row) * S_ + hi * 4;

    for (int kt = 0; kt < 32; ++kt) {
        if (kt + 1 < 32) { stageK(cur ^ 1, kt + 1); stageV(cur ^ 1, kt + 1); }

        f32x16 s0, s1;
        #pragma unroll
        for (int i = 0; i < 16; ++i) { s0[i] = 0.f; s1[i] = 0.f; }
        #pragma unroll
        for (int c = 0; c < 4; ++c) {
            f16x8 kf = *reinterpret_cast<const f16x8*>(
                (const char*)ksd + cur * 8192 + swz(lo, c * 32 + hi * 16));
            s0 = __builtin_amdgcn_mfma_f32_32x32x16_f16(kf, qf[c], s0, 0, 0, 0);
        }
        #pragma unroll
        for (int c = 0; c < 4; ++c) {
            f16x8 kf = *reinterpret_cast<const f16x8*>(
                (const char*)ksd + cur * 8192 + swz(lo + 32, c * 32 + hi * 16));
            s1 = __builtin_amdgcn_mfma_f32_32x32x16_f16(kf, qf[c], s1, 0, 0, 0);
        }

        const unsigned m0 = mbits[kt * 2]     >> (hi * 4);
        const unsigned m1 = mbits[kt * 2 + 1] >> (hi * 4);
        float p0[16], p1[16];
        #pragma unroll
        for (int q4 = 0; q4 < 4; ++q4)
            #pragma unroll
            for (int j = 0; j < 4; ++j) {
                float e0 = __builtin_amdgcn_exp2f(s0[q4 * 4 + j]);
                float e1 = __builtin_amdgcn_exp2f(s1[q4 * 4 + j]);
                p0[q4 * 4 + j] = ((m0 >> (q4 * 8 + j)) & 1) ? e0 : 0.0f;
                p1[q4 * 4 + j] = ((m1 >> (q4 * 8 + j)) & 1) ? e1 : 0.0f;
            }

        // normalized attn stores: 8 x float4, 256B/row/tile contiguous
        #pragma unroll
        for (int q4 = 0; q4 < 4; ++q4) {
            f32x4 o0 = {p0[q4 * 4 + 0] * invl, p0[q4 * 4 + 1] * invl,
                        p0[q4 * 4 + 2] * invl, p0[q4 * 4 + 3] * invl};
            *reinterpret_cast<f32x4*>(ab + (size_t)kt * 64 + q4 * 8) = o0;
            f32x4 o1 = {p1[q4 * 4 + 0] * invl, p1[q4 * 4 + 1] * invl,
                        p1[q4 * 4 + 2] * invl, p1[q4 * 4 + 3] * invl};
            *reinterpret_cast<f32x4*>(ab + (size_t)kt * 64 + 32 + q4 * 8) = o1;
        }

        // pack P into f16 words: wa[h][q4] = (j0,j1), wb[h][q4] = (j2,j3)
        unsigned wa[2][4], wb[2][4];
        #pragma unroll
        for (int q4 = 0; q4 < 4; ++q4) {
            wa[0][q4] = pk16(p0[q4 * 4 + 0], p0[q4 * 4 + 1]);
            wb[0][q4] = pk16(p0[q4 * 4 + 2], p0[q4 * 4 + 3]);
            wa[1][q4] = pk16(p1[q4 * 4 + 0], p1[q4 * 4 + 1]);
            wb[1][q4] = pk16(p1[q4 * 4 + 2], p1[q4 * 4 + 3]);
        }

        // 4 P B-frags (k = c2*16 + hi*8 ..+8) + PV MFMAs
        #pragma unroll
        for (int c2 = 0; c2 < 4; ++c2) {
            const int hh = c2 >> 1, base = (c2 & 1) * 2;
            unsigned a0 = wa[hh][base], a1 = wa[hh][base + 1];
            unsigned b0 = wb[hh][base], b1 = wb[hh][base + 1];
            unsigned sa = H1 ? a0 : a1;               // send index = base + (1-H)
            unsigned sb = H1 ? b0 : b1;
            unsigned ra = (unsigned)__shfl_xor((int)sa, 32, 64);
            unsigned rb = (unsigned)__shfl_xor((int)sb, 32, 64);
            unsigned oa = H1 ? a1 : a0;               // own index = base + H
            unsigned ob = H1 ? b1 : b0;
            uint4 bw = H1 ? (uint4){ra, rb, oa, ob} : (uint4){oa, ob, ra, rb};
            f16x8 pf = __builtin_bit_cast(f16x8, bw);

            f16x8 va0 = *reinterpret_cast<const f16x8*>(
                (const char*)vsd + cur * 8192 + swz(lo, c2 * 32 + hi * 16));
            f16x8 va1 = *reinterpret_cast<const f16x8*>(
                (const char*)vsd + cur * 8192 + swz(lo + 32, c2 * 32 + hi * 16));
            oc0 = __builtin_amdgcn_mfma_f32_32x32x16_f16(va0, pf, oc0, 0, 0, 0);
            oc1 = __builtin_amdgcn_mfma_f32_32x32x16_f16(va1, pf, oc1, 0, 0, 0);
        }
        __syncthreads();
        cur ^= 1;
    }

    // ---- ctx store: lane owns its row, no cross-wave reduction ----
    f16* cb = ch + (size_t)(b * S_ + row) * D_ + h * DH_;
    #pragma unroll
    for (int q4 = 0; q4 < 4; ++q4) {
        int d0 = 8 * q4 + 4 * hi;
        f16x4 v0 = {(f16)(oc0[4 * q4 + 0] * invl), (f16)(oc0[4 * q4 + 1] * invl),
                    (f16)(oc0[4 * q4 + 2] * invl), (f16)(oc0[4 * q4 + 3] * invl)};
        *reinterpret_cast<f16x4*>(cb + d0) = v0;
        f16x4 v1 = {(f16)(oc1[4 * q4 + 0] * invl), (f16)(oc1[4 * q4 + 1] * invl),
                    (f16)(oc1[4 * q4 + 2] * invl), (f16)(oc1[4 * q4 + 3] * invl)};
        *reinterpret_cast<f16x4*>(cb + 32 + d0) = v1;
    }
}

extern "C" void kernel_launch(void* const* d_in, const int* in_sizes, int n_in,
                              void* d_out, int out_size, void* d_ws, size_t ws_size,
                              hipStream_t stream) {
    const float* query = (const float*)d_in[0];
    const float* key   = (const float*)d_in[1];
    const float* value = (const float*)d_in[2];
    const int*   kmask = (const int*)d_in[3];
    const float* Wq = (const float*)d_in[4];
    const float* bq = (const float*)d_in[5];
    const float* Wk = (const float*)d_in[6];
    const float* bk = (const float*)d_in[7];
    const float* Wv = (const float*)d_in[8];
    const float* bv = (const float*)d_in[9];
    const float* Wo = (const float*)d_in[10];
    const float* bo = (const float*)d_in[11];

    float* out  = (float*)d_out;
    float* attn = out + (size_t)B_ * S_ * D_;

    const size_t NE = (size_t)B_ * S_ * D_;
    f16* qhp = (f16*)d_ws;
    f16* khp = qhp + NE;
    f16* vtg = khp + NE;             // per-head transposed V: [(b*16+h)*64+d][s]
    f16* chx = vtg + NE;             // 32 MB of ws total

    const float qscale = 0.125f * 1.44269504088896340736f;   // (1/sqrt(DH)) * log2(e)

    qkv_gemm<<<dim3(8, 32, 3), 256, 0, stream>>>(query, key, value, Wq, Wk, Wv,
                                                 bq, bk, bv, qhp, khp, vtg, qscale);

    attn_fused<<<dim3(B_ * H_ * (S_ / 128)), 256, 0, stream>>>(qhp, khp, vtg, kmask,
                                                               attn, chx);

    gemm_out<<<dim3(8, 32), 256, 0, stream>>>(chx, Wo, bo, out);
}